// Round 1
// baseline (3538.199 us; speedup 1.0000x reference)
//
#include <hip/hip_runtime.h>
#include <cstddef>

#define TT 512
#define BB 8
#define HH 1024
#define MM 32
#define NVOCAB 32000
#define NROWS (TT * BB)   // 4096

// ---------------------------------------------------------------------------
// 1) hidden[r][h] = emb[x[r]][h] + pos_emb[t][h],  r = t*8+b
// ---------------------------------------------------------------------------
__global__ __launch_bounds__(256) void k_embed(const int* __restrict__ x,
                                               const float* __restrict__ emb,
                                               const float* __restrict__ pos,
                                               float* __restrict__ out) {
    int r = blockIdx.x;         // 0..4095
    int t = r >> 3;             // /8
    int idx = x[r];
    const float4* e = (const float4*)(emb + (size_t)idx * HH);
    const float4* p = (const float4*)(pos + (size_t)t * HH);
    float4* o = (float4*)(out + (size_t)r * HH);
    int i = threadIdx.x;        // 0..255, 4 floats each
    float4 ev = e[i], pv = p[i];
    o[i] = make_float4(ev.x + pv.x, ev.y + pv.y, ev.z + pv.z, ev.w + pv.w);
}

// ---------------------------------------------------------------------------
// 2) q = row @ Wq [1024x32], k = row @ Wk; a = softmax(q/2), b = softmax(k/2)
//    one block (256 thr) per row; 4 threads per output column, shfl-reduce.
// ---------------------------------------------------------------------------
__global__ __launch_bounds__(256) void k_proj_softmax(const float* __restrict__ hid,
                                                      const float* __restrict__ Wq,
                                                      const float* __restrict__ Wk,
                                                      float* __restrict__ aout,
                                                      float* __restrict__ bout_) {
    __shared__ float xs[HH];
    __shared__ float qk[64];
    int r = blockIdx.x;
    int tid = threadIdx.x;
    ((float4*)xs)[tid] = ((const float4*)(hid + (size_t)r * HH))[tid];
    __syncthreads();

    int col = tid >> 2;       // 0..63 (0..31 -> q, 32..63 -> k)
    int seg = tid & 3;        // k-range quarter
    const float* W = (col < 32) ? Wq : Wk;
    int c = col & 31;
    float s = 0.f;
    int h0 = seg * 256;
    #pragma unroll 8
    for (int hh = 0; hh < 256; ++hh)
        s = fmaf(xs[h0 + hh], W[(size_t)(h0 + hh) * MM + c], s);
    s += __shfl_down(s, 1);
    s += __shfl_down(s, 2);
    if (seg == 0) qk[col] = s;
    __syncthreads();

    if (tid < 64) {                       // exactly wave 0
        float v = qk[tid] * 0.5f;         // / tau (tau = 2)
        float m = v;
        #pragma unroll
        for (int o = 16; o >= 1; o >>= 1) m = fmaxf(m, __shfl_xor(m, o));
        float e = expf(v - m);
        float ssum = e;
        #pragma unroll
        for (int o = 16; o >= 1; o >>= 1) ssum += __shfl_xor(ssum, o);
        float res = e / ssum;
        if (tid < 32) aout[(size_t)r * MM + tid] = res;
        else          bout_[(size_t)r * MM + (tid - 32)] = res;
    }
}

// ---------------------------------------------------------------------------
// 3) leaky associative scan. One block per batch element; thread (i,j) owns
//    mem[b][i][j]; a/b rows staged into LDS in chunks of 128 timesteps.
// ---------------------------------------------------------------------------
#define CHUNK 128
__global__ __launch_bounds__(1024) void k_scan(const float* __restrict__ a,
                                               const float* __restrict__ bsm,
                                               float* __restrict__ spk) {
    __shared__ float sa[CHUNK * MM];
    __shared__ float sb[CHUNK * MM];
    int bb = blockIdx.x;            // batch
    int tid = threadIdx.x;          // 0..1023
    int i = tid >> 5, j = tid & 31;
    float mem = 0.f;
    for (int t0 = 0; t0 < TT; t0 += CHUNK) {
        __syncthreads();
        for (int idx = tid; idx < CHUNK * MM; idx += 1024) {
            int tt = idx >> 5, m = idx & 31;
            size_t g = ((size_t)(t0 + tt) * BB + bb) * MM + m;
            sa[idx] = a[g];
            sb[idx] = bsm[g];
        }
        __syncthreads();
        for (int tt = 0; tt < CHUNK; ++tt) {
            float av = sa[tt * MM + i];
            float bv = sb[tt * MM + j];
            mem = fmaf(0.9f, mem, av * bv);
            float sv = (mem > 1.0f) ? 1.0f : 0.0f;
            spk[((size_t)(t0 + tt) * BB + bb) * HH + tid] = sv;
            mem -= sv;   // THR = 1
        }
    }
}

// ---------------------------------------------------------------------------
// 4) C[NROWS][N] = (relu?)(A[NROWS][1024] @ W[1024][N] + bias)
//    64x64 tile / block of 256, 4x4 micro-tile, BK=16.
// ---------------------------------------------------------------------------
template <int DO_RELU>
__global__ __launch_bounds__(256) void k_gemm(const float* __restrict__ A,
                                              const float* __restrict__ W,
                                              const float* __restrict__ bias,
                                              float* __restrict__ C, int N) {
    __shared__ float As[16][64];    // [k][row]
    __shared__ float Ws[16][64];    // [k][col]
    int tid = threadIdx.x;
    int brow = blockIdx.y * 64;
    int bcol = blockIdx.x * 64;
    int tx = tid & 15, ty = tid >> 4;
    float acc[4][4] = {{0.f}};

    for (int k0 = 0; k0 < HH; k0 += 16) {
        {   // A tile: row = tid>>2 (0..63), 4 consecutive k
            int rr = tid >> 2;
            int kk = (tid & 3) * 4;
            float4 v = *(const float4*)(A + (size_t)(brow + rr) * HH + k0 + kk);
            As[kk + 0][rr] = v.x; As[kk + 1][rr] = v.y;
            As[kk + 2][rr] = v.z; As[kk + 3][rr] = v.w;
        }
        {   // W tile: k-row = tid>>4 (0..15), 4 consecutive cols
            int kk = tid >> 4;
            int cc = (tid & 15) * 4;
            float4 v = *(const float4*)(W + (size_t)(k0 + kk) * N + bcol + cc);
            *(float4*)&Ws[kk][cc] = v;
        }
        __syncthreads();
        #pragma unroll
        for (int kk = 0; kk < 16; ++kk) {
            float af[4], bf[4];
            #pragma unroll
            for (int u = 0; u < 4; ++u) af[u] = As[kk][ty * 4 + u];
            #pragma unroll
            for (int u = 0; u < 4; ++u) bf[u] = Ws[kk][tx * 4 + u];
            #pragma unroll
            for (int i2 = 0; i2 < 4; ++i2)
                #pragma unroll
                for (int j2 = 0; j2 < 4; ++j2)
                    acc[i2][j2] = fmaf(af[i2], bf[j2], acc[i2][j2]);
        }
        __syncthreads();
    }

    #pragma unroll
    for (int i2 = 0; i2 < 4; ++i2) {
        int row = brow + ty * 4 + i2;
        float4 v;
        float* pv = &v.x;
        #pragma unroll
        for (int j2 = 0; j2 < 4; ++j2) {
            float t = acc[i2][j2] + bias[bcol + tx * 4 + j2];
            if (DO_RELU) t = fmaxf(t, 0.f);
            pv[j2] = t;
        }
        *(float4*)(C + (size_t)row * N + bcol + tx * 4) = v;
    }
}

// ---------------------------------------------------------------------------
// 5) in-place row LayerNorm (biased var, eps=1e-5)
// ---------------------------------------------------------------------------
__global__ __launch_bounds__(256) void k_layernorm(float* __restrict__ X,
                                                   const float* __restrict__ g,
                                                   const float* __restrict__ bta) {
    __shared__ float rs[4], rss[4];
    int r = blockIdx.x;
    int tid = threadIdx.x;
    float* row = X + (size_t)r * HH;
    float4 v = ((float4*)row)[tid];
    float s = v.x + v.y + v.z + v.w;
    float ss = v.x * v.x + v.y * v.y + v.z * v.z + v.w * v.w;
    #pragma unroll
    for (int o = 32; o >= 1; o >>= 1) {
        s += __shfl_down(s, o);
        ss += __shfl_down(ss, o);
    }
    int w = tid >> 6;
    if ((tid & 63) == 0) { rs[w] = s; rss[w] = ss; }
    __syncthreads();
    float S = rs[0] + rs[1] + rs[2] + rs[3];
    float SS = rss[0] + rss[1] + rss[2] + rss[3];
    float mu = S * (1.f / HH);
    float var = SS * (1.f / HH) - mu * mu;
    float inv = rsqrtf(var + 1e-5f);
    float4 gg = ((const float4*)g)[tid];
    float4 bb = ((const float4*)bta)[tid];
    float4 o;
    o.x = (v.x - mu) * inv * gg.x + bb.x;
    o.y = (v.y - mu) * inv * gg.y + bb.y;
    o.z = (v.z - mu) * inv * gg.z + bb.z;
    o.w = (v.w - mu) * inv * gg.w + bb.w;
    ((float4*)row)[tid] = o;
}

// ---------------------------------------------------------------------------
extern "C" void kernel_launch(void* const* d_in, const int* in_sizes, int n_in,
                              void* d_out, int out_size, void* d_ws, size_t ws_size,
                              hipStream_t stream) {
    const int*   x    = (const int*)d_in[0];
    const float* emb  = (const float*)d_in[1];
    const float* pos  = (const float*)d_in[2];
    const float* Wq1  = (const float*)d_in[3];
    const float* Wk1  = (const float*)d_in[4];
    const float* Wq2  = (const float*)d_in[5];
    const float* Wk2  = (const float*)d_in[6];
    const float* Wq3  = (const float*)d_in[7];
    const float* Wk3  = (const float*)d_in[8];
    const float* W2   = (const float*)d_in[9];
    const float* b2   = (const float*)d_in[10];
    const float* W3   = (const float*)d_in[11];
    const float* b3   = (const float*)d_in[12];
    const float* W4   = (const float*)d_in[13];
    const float* b4   = (const float*)d_in[14];
    const float* Wout = (const float*)d_in[15];
    const float* bout = (const float*)d_in[16];
    const float* ln2g = (const float*)d_in[17];
    const float* ln2b = (const float*)d_in[18];
    const float* ln3g = (const float*)d_in[19];
    const float* ln3b = (const float*)d_in[20];

    float* h   = (float*)d_ws;                       // [4096][1024]
    float* spk = h + (size_t)NROWS * HH;             // [4096][1024]
    float* pa  = spk + (size_t)NROWS * HH;           // [4096][32]
    float* pb  = pa + (size_t)NROWS * MM;            // [4096][32]
    float* out = (float*)d_out;                      // [4096][32000]

    dim3 gmid(HH / 64, NROWS / 64);                  // 16 x 64
    dim3 gout(NVOCAB / 64, NROWS / 64);              // 500 x 64

    k_embed<<<NROWS, 256, 0, stream>>>(x, emb, pos, h);

    // layer 1
    k_proj_softmax<<<NROWS, 256, 0, stream>>>(h, Wq1, Wk1, pa, pb);
    k_scan<<<BB, 1024, 0, stream>>>(pa, pb, spk);
    k_gemm<1><<<gmid, 256, 0, stream>>>(spk, W2, b2, h, HH);
    k_layernorm<<<NROWS, 256, 0, stream>>>(h, ln2g, ln2b);

    // layer 2
    k_proj_softmax<<<NROWS, 256, 0, stream>>>(h, Wq2, Wk2, pa, pb);
    k_scan<<<BB, 1024, 0, stream>>>(pa, pb, spk);
    k_gemm<1><<<gmid, 256, 0, stream>>>(spk, W3, b3, h, HH);
    k_layernorm<<<NROWS, 256, 0, stream>>>(h, ln3g, ln3b);

    // layer 3
    k_proj_softmax<<<NROWS, 256, 0, stream>>>(h, Wq3, Wk3, pa, pb);
    k_scan<<<BB, 1024, 0, stream>>>(pa, pb, spk);
    k_gemm<1><<<gmid, 256, 0, stream>>>(spk, W4, b4, h, HH);

    // output projection
    k_gemm<0><<<gout, 256, 0, stream>>>(h, Wout, bout, out, NVOCAB);
}

// Round 3
// 1051.218 us; speedup vs baseline: 3.3658x; 3.3658x over previous
//
#include <hip/hip_runtime.h>
#include <hip/hip_bf16.h>
#include <cstddef>

#define TT 512
#define BB 8
#define HH 1024
#define MM 32
#define NVOCAB 32000
#define NROWS (TT * BB)   // 4096

typedef __attribute__((ext_vector_type(8))) short bf16x8;
typedef __attribute__((ext_vector_type(4))) float f32x4;

__device__ __forceinline__ void gload_lds16(const void* g, void* l) {
    __builtin_amdgcn_global_load_lds(
        (const __attribute__((address_space(1))) void*)g,
        (__attribute__((address_space(3))) void*)l, 16, 0, 0);
}

__device__ __forceinline__ unsigned short bf16_bits(float f) {
    __hip_bfloat16 h = __float2bfloat16(f);
    return *reinterpret_cast<unsigned short*>(&h);
}

// ---------------------------------------------------------------------------
// 1) hidden[r][h] = emb[x[r]][h] + pos_emb[t][h],  r = t*8+b
// ---------------------------------------------------------------------------
__global__ __launch_bounds__(256) void k_embed(const int* __restrict__ x,
                                               const float* __restrict__ emb,
                                               const float* __restrict__ pos,
                                               float* __restrict__ out) {
    int r = blockIdx.x;
    int t = r >> 3;
    int idx = x[r];
    const float4* e = (const float4*)(emb + (size_t)idx * HH);
    const float4* p = (const float4*)(pos + (size_t)t * HH);
    float4* o = (float4*)(out + (size_t)r * HH);
    int i = threadIdx.x;
    float4 ev = e[i], pv = p[i];
    o[i] = make_float4(ev.x + pv.x, ev.y + pv.y, ev.z + pv.z, ev.w + pv.w);
}

// ---------------------------------------------------------------------------
// 2) q/k proj + tau-softmax
// ---------------------------------------------------------------------------
__global__ __launch_bounds__(256) void k_proj_softmax(const float* __restrict__ hid,
                                                      const float* __restrict__ Wq,
                                                      const float* __restrict__ Wk,
                                                      float* __restrict__ aout,
                                                      float* __restrict__ bout_) {
    __shared__ float xs[HH];
    __shared__ float qk[64];
    int r = blockIdx.x;
    int tid = threadIdx.x;
    ((float4*)xs)[tid] = ((const float4*)(hid + (size_t)r * HH))[tid];
    __syncthreads();

    int col = tid >> 2;
    int seg = tid & 3;
    const float* W = (col < 32) ? Wq : Wk;
    int c = col & 31;
    float s = 0.f;
    int h0 = seg * 256;
    #pragma unroll 8
    for (int hh = 0; hh < 256; ++hh)
        s = fmaf(xs[h0 + hh], W[(size_t)(h0 + hh) * MM + c], s);
    s += __shfl_down(s, 1);
    s += __shfl_down(s, 2);
    if (seg == 0) qk[col] = s;
    __syncthreads();

    if (tid < 64) {
        float v = qk[tid] * 0.5f;
        float m = v;
        #pragma unroll
        for (int o = 16; o >= 1; o >>= 1) m = fmaxf(m, __shfl_xor(m, o));
        float e = expf(v - m);
        float ssum = e;
        #pragma unroll
        for (int o = 16; o >= 1; o >>= 1) ssum += __shfl_xor(ssum, o);
        float res = e / ssum;
        if (tid < 32) aout[(size_t)r * MM + tid] = res;
        else          bout_[(size_t)r * MM + (tid - 32)] = res;
    }
}

// ---------------------------------------------------------------------------
// 3) leaky associative scan -> spikes directly in bf16 (0/1 exact)
// ---------------------------------------------------------------------------
#define CHUNK 128
__global__ __launch_bounds__(1024) void k_scan(const float* __restrict__ a,
                                               const float* __restrict__ bsm,
                                               __hip_bfloat16* __restrict__ spk) {
    __shared__ float sa[CHUNK * MM];
    __shared__ float sb[CHUNK * MM];
    int bb = blockIdx.x;
    int tid = threadIdx.x;
    int i = tid >> 5, j = tid & 31;
    float mem = 0.f;
    for (int t0 = 0; t0 < TT; t0 += CHUNK) {
        __syncthreads();
        for (int idx = tid; idx < CHUNK * MM; idx += 1024) {
            int tt = idx >> 5, m = idx & 31;
            size_t g = ((size_t)(t0 + tt) * BB + bb) * MM + m;
            sa[idx] = a[g];
            sb[idx] = bsm[g];
        }
        __syncthreads();
        for (int tt = 0; tt < CHUNK; ++tt) {
            float av = sa[tt * MM + i];
            float bv = sb[tt * MM + j];
            mem = fmaf(0.9f, mem, av * bv);
            float sv = (mem > 1.0f) ? 1.0f : 0.0f;
            spk[((size_t)(t0 + tt) * BB + bb) * HH + tid] = __float2bfloat16(sv);
            mem -= sv;
        }
    }
}

// ---------------------------------------------------------------------------
// 4a) W [K][N] fp32 -> Wt [N][K] bf16  (tiled transpose + convert)
// ---------------------------------------------------------------------------
__global__ __launch_bounds__(256) void k_transpose_cvt(const float* __restrict__ W,
                                                       __hip_bfloat16* __restrict__ Wt,
                                                       int K, int N) {
    __shared__ float t[32][33];
    int n0 = blockIdx.x * 32;
    int k0 = blockIdx.y * 32;
    int tx = threadIdx.x & 31, ty = threadIdx.x >> 5;   // ty 0..7
    #pragma unroll
    for (int r = 0; r < 4; ++r)
        t[ty + r * 8][tx] = W[(size_t)(k0 + ty + r * 8) * N + n0 + tx];
    __syncthreads();
    #pragma unroll
    for (int r = 0; r < 4; ++r)
        Wt[(size_t)(n0 + ty + r * 8) * K + k0 + tx] = __float2bfloat16(t[tx][ty + r * 8]);
}

// ---------------------------------------------------------------------------
// 4b) fp32 -> bf16 elementwise (4/thread)
// ---------------------------------------------------------------------------
__global__ __launch_bounds__(256) void k_f2b(const float* __restrict__ X,
                                             __hip_bfloat16* __restrict__ Y) {
    int i = blockIdx.x * 256 + threadIdx.x;
    float4 v = ((const float4*)X)[i];
    ushort4 o;
    o.x = bf16_bits(v.x);
    o.y = bf16_bits(v.y);
    o.z = bf16_bits(v.z);
    o.w = bf16_bits(v.w);
    ((ushort4*)Y)[i] = o;
}

// ---------------------------------------------------------------------------
// 5) bf16 MFMA GEMM, m97 structure: 128x128 tile, 4 waves (2x2), BK=32,
//    global_load_lds width 16, single LDS buffer, 2 barriers / K-step.
//    A [M][K] bf16 row-major, Bt [N][K] bf16 row-major (pre-transposed).
//    C fp32 [M][N] = (relu?)(A @ Bt^T + bias)
// ---------------------------------------------------------------------------
template <int DO_RELU>
__global__ __launch_bounds__(256) void k_gemm_bf16(const __hip_bfloat16* __restrict__ A,
                                                   const __hip_bfloat16* __restrict__ Bt,
                                                   const float* __restrict__ bias,
                                                   float* __restrict__ C,
                                                   int N, int K) {
    __shared__ __align__(16) __hip_bfloat16 As[128 * 32];
    __shared__ __align__(16) __hip_bfloat16 Bs[128 * 32];
    int tid = threadIdx.x;
    int lane = tid & 63;
    int w = tid >> 6;
    int wr = w >> 1, wc = w & 1;
    int brow = blockIdx.y * 128;
    int bcol = blockIdx.x * 128;

    f32x4 acc[4][4] = {};

    // staging: round r covers LDS bytes [r*4096 + tid*16]
    // -> element (r*2048 + tid*8) -> row r*64 + tid/4, col (tid&3)*8
    const __hip_bfloat16* gA = A  + (size_t)(brow + (tid >> 2)) * K + (tid & 3) * 8;
    const __hip_bfloat16* gB = Bt + (size_t)(bcol + (tid >> 2)) * K + (tid & 3) * 8;
    __hip_bfloat16* lA0 = As + (size_t)(w * 512);   // wave-uniform base, round 0
    __hip_bfloat16* lB0 = Bs + (size_t)(w * 512);
    const size_t rstep = (size_t)64 * K;            // +64 rows for round 1

    int r0 = wr * 64 + (lane & 15);
    int c0 = wc * 64 + (lane & 15);
    int kb = lane >> 4;

    for (int k0 = 0; k0 < K; k0 += 32) {
        gload_lds16(gA + k0,         lA0);
        gload_lds16(gA + k0 + rstep, lA0 + 2048);
        gload_lds16(gB + k0,         lB0);
        gload_lds16(gB + k0 + rstep, lB0 + 2048);
        __syncthreads();

        bf16x8 af[4], bfr[4];
        #pragma unroll
        for (int m = 0; m < 4; ++m)
            af[m] = ((const bf16x8*)As)[(r0 + m * 16) * 4 + kb];
        #pragma unroll
        for (int n = 0; n < 4; ++n)
            bfr[n] = ((const bf16x8*)Bs)[(c0 + n * 16) * 4 + kb];
        #pragma unroll
        for (int m = 0; m < 4; ++m)
            #pragma unroll
            for (int n = 0; n < 4; ++n)
                acc[m][n] = __builtin_amdgcn_mfma_f32_16x16x32_bf16(af[m], bfr[n], acc[m][n], 0, 0, 0);
        __syncthreads();
    }

    int ccol = bcol + wc * 64 + (lane & 15);
    int crow = brow + wr * 64 + ((lane >> 4) << 2);
    #pragma unroll
    for (int n = 0; n < 4; ++n) {
        float bv = bias[ccol + n * 16];
        #pragma unroll
        for (int m = 0; m < 4; ++m) {
            #pragma unroll
            for (int q = 0; q < 4; ++q) {
                float v = acc[m][n][q] + bv;
                if (DO_RELU) v = fmaxf(v, 0.f);
                C[(size_t)(crow + m * 16 + q) * N + ccol + n * 16] = v;
            }
        }
    }
}

// ---------------------------------------------------------------------------
// 6) in-place row LayerNorm
// ---------------------------------------------------------------------------
__global__ __launch_bounds__(256) void k_layernorm(float* __restrict__ X,
                                                   const float* __restrict__ g,
                                                   const float* __restrict__ bta) {
    __shared__ float rs[4], rss[4];
    int r = blockIdx.x;
    int tid = threadIdx.x;
    float* row = X + (size_t)r * HH;
    float4 v = ((float4*)row)[tid];
    float s = v.x + v.y + v.z + v.w;
    float ss = v.x * v.x + v.y * v.y + v.z * v.z + v.w * v.w;
    #pragma unroll
    for (int o = 32; o >= 1; o >>= 1) {
        s += __shfl_down(s, o);
        ss += __shfl_down(ss, o);
    }
    int w = tid >> 6;
    if ((tid & 63) == 0) { rs[w] = s; rss[w] = ss; }
    __syncthreads();
    float S = rs[0] + rs[1] + rs[2] + rs[3];
    float SS = rss[0] + rss[1] + rss[2] + rss[3];
    float mu = S * (1.f / HH);
    float var = SS * (1.f / HH) - mu * mu;
    float inv = rsqrtf(var + 1e-5f);
    float4 gg = ((const float4*)g)[tid];
    float4 bb = ((const float4*)bta)[tid];
    float4 o;
    o.x = (v.x - mu) * inv * gg.x + bb.x;
    o.y = (v.y - mu) * inv * gg.y + bb.y;
    o.z = (v.z - mu) * inv * gg.z + bb.z;
    o.w = (v.w - mu) * inv * gg.w + bb.w;
    ((float4*)row)[tid] = o;
}

// ---------------------------------------------------------------------------
extern "C" void kernel_launch(void* const* d_in, const int* in_sizes, int n_in,
                              void* d_out, int out_size, void* d_ws, size_t ws_size,
                              hipStream_t stream) {
    const int*   x    = (const int*)d_in[0];
    const float* emb  = (const float*)d_in[1];
    const float* pos  = (const float*)d_in[2];
    const float* Wq1  = (const float*)d_in[3];
    const float* Wk1  = (const float*)d_in[4];
    const float* Wq2  = (const float*)d_in[5];
    const float* Wk2  = (const float*)d_in[6];
    const float* Wq3  = (const float*)d_in[7];
    const float* Wk3  = (const float*)d_in[8];
    const float* W2   = (const float*)d_in[9];
    const float* b2   = (const float*)d_in[10];
    const float* W3   = (const float*)d_in[11];
    const float* b3   = (const float*)d_in[12];
    const float* W4   = (const float*)d_in[13];
    const float* b4   = (const float*)d_in[14];
    const float* Wout = (const float*)d_in[15];
    const float* bout = (const float*)d_in[16];
    const float* ln2g = (const float*)d_in[17];
    const float* ln2b = (const float*)d_in[18];
    const float* ln3g = (const float*)d_in[19];
    const float* ln3b = (const float*)d_in[20];

    char* wsp = (char*)d_ws;
    float* h   = (float*)wsp;                 wsp += (size_t)NROWS * HH * 4;   // 16 MB
    float* pa  = (float*)wsp;                 wsp += (size_t)NROWS * MM * 4;
    float* pb  = (float*)wsp;                 wsp += (size_t)NROWS * MM * 4;
    __hip_bfloat16* spkb = (__hip_bfloat16*)wsp; wsp += (size_t)NROWS * HH * 2;  // 8 MB
    __hip_bfloat16* hb   = (__hip_bfloat16*)wsp; wsp += (size_t)NROWS * HH * 2;  // 8 MB
    __hip_bfloat16* W2t  = (__hip_bfloat16*)wsp; wsp += (size_t)HH * HH * 2;     // 2 MB
    __hip_bfloat16* W3t  = (__hip_bfloat16*)wsp; wsp += (size_t)HH * HH * 2;
    __hip_bfloat16* W4t  = (__hip_bfloat16*)wsp; wsp += (size_t)HH * HH * 2;
    __hip_bfloat16* Wot  = (__hip_bfloat16*)wsp; wsp += (size_t)NVOCAB * HH * 2; // 64 MB
    float* out = (float*)d_out;

    // weight prep (bf16, transposed to [N][K])
    k_transpose_cvt<<<dim3(HH / 32, HH / 32), 256, 0, stream>>>(W2, W2t, HH, HH);
    k_transpose_cvt<<<dim3(HH / 32, HH / 32), 256, 0, stream>>>(W3, W3t, HH, HH);
    k_transpose_cvt<<<dim3(HH / 32, HH / 32), 256, 0, stream>>>(W4, W4t, HH, HH);
    k_transpose_cvt<<<dim3(NVOCAB / 32, HH / 32), 256, 0, stream>>>(Wout, Wot, HH, NVOCAB);

    dim3 gmid(HH / 128, NROWS / 128);         // 8 x 32
    dim3 gout(NVOCAB / 128, NROWS / 128);     // 250 x 32

    k_embed<<<NROWS, 256, 0, stream>>>(x, emb, pos, h);

    // layer 1
    k_proj_softmax<<<NROWS, 256, 0, stream>>>(h, Wq1, Wk1, pa, pb);
    k_scan<<<BB, 1024, 0, stream>>>(pa, pb, spkb);
    k_gemm_bf16<1><<<gmid, 256, 0, stream>>>(spkb, W2t, b2, h, HH, HH);
    k_layernorm<<<NROWS, 256, 0, stream>>>(h, ln2g, ln2b);

    // layer 2
    k_proj_softmax<<<NROWS, 256, 0, stream>>>(h, Wq2, Wk2, pa, pb);
    k_scan<<<BB, 1024, 0, stream>>>(pa, pb, spkb);
    k_gemm_bf16<1><<<gmid, 256, 0, stream>>>(spkb, W3t, b3, h, HH, HH);
    k_layernorm<<<NROWS, 256, 0, stream>>>(h, ln3g, ln3b);

    // layer 3
    k_proj_softmax<<<NROWS, 256, 0, stream>>>(h, Wq3, Wk3, pa, pb);
    k_scan<<<BB, 1024, 0, stream>>>(pa, pb, spkb);
    k_gemm_bf16<1><<<gmid, 256, 0, stream>>>(spkb, W4t, b4, h, HH, HH);

    // output projection
    k_f2b<<<NROWS * HH / 1024, 256, 0, stream>>>(h, hb);
    k_gemm_bf16<0><<<gout, 256, 0, stream>>>(hb, Wot, bout, out, NVOCAB, HH);
}